// Round 1
// baseline (295.056 us; speedup 1.0000x reference)
//
#include <hip/hip_runtime.h>

// Problem constants (B=4, C=256, H=W=64, K=7, GROUPS=16, GC=16, CR=64)
#define BN   4
#define CC   256
#define CR   64
#define HH   64
#define WW   64
#define HWP  4096        // H*W
#define KS   7
#define KK   49
#define NG   16
#define GC   16
#define K2G  784         // KK * NG
#define BN_EPS 1e-5f
#define GSPLIT 4         // groups handled per block: NG/GSPLIT = 4

// ---------------------------------------------------------------------------
// Kernel 1: x[b,o,p] = ReLU( BN( sum_c w1[o,c]*guide[b,c,p] ) )
// One thread = one pixel x 16 output channels. 65536 threads = 256 blocks.
// guide reads coalesced (consecutive lanes -> consecutive pixels); w1 index
// wave-uniform -> scalar loads.
// ---------------------------------------------------------------------------
__global__ __launch_bounds__(256) void conv1_bn_relu(
    const float* __restrict__ guide, const float* __restrict__ w1,
    const float* __restrict__ gamma, const float* __restrict__ beta,
    const float* __restrict__ mean,  const float* __restrict__ var,
    float* __restrict__ x)
{
    const int t   = blockIdx.x * 256 + threadIdx.x;
    const int og  = t >> 14;        // 0..3  (uniform within a block: 16384%256==0)
    const int pix = t & 16383;      // b*4096 + p
    const int b   = pix >> 12;
    const int p   = pix & 4095;
    const int obase = og * 16;

    const float* gp = guide + (size_t)(b * CC) * HWP + p;

    float acc[16];
#pragma unroll
    for (int j = 0; j < 16; ++j) acc[j] = 0.f;

    for (int c = 0; c < CC; ++c) {
        const float g = gp[(size_t)c * HWP];
#pragma unroll
        for (int j = 0; j < 16; ++j)
            acc[j] = fmaf(w1[(obase + j) * CC + c], g, acc[j]);
    }

#pragma unroll
    for (int j = 0; j < 16; ++j) {
        const int o = obase + j;
        const float inv = gamma[o] * rsqrtf(var[o] + BN_EPS);
        const float v   = fmaf(acc[j], inv, beta[o] - mean[o] * inv);
        x[(size_t)(b * CR + o) * HWP + p] = fmaxf(v, 0.f);
    }
}

// ---------------------------------------------------------------------------
// Kernel 2: per block = (b, row h, quad of groups gs).
//   stage x row tile xs[64 ch][64 w] in LDS,
//   for each of 4 groups: compute wg[k][w] = w2 row dot xs col + b2 (in LDS),
//   then 4 output channels per thread: out = sum_k wg[k][w]*feat[c][h+di][w+dj]
//   (+ residual). Feature loads coalesced (lane = w).
// Grid: B*H*GSPLIT = 1024 blocks of 256 threads.
// ---------------------------------------------------------------------------
__global__ __launch_bounds__(256) void conv2_agg(
    const float* __restrict__ x,  const float* __restrict__ w2,
    const float* __restrict__ b2, const float* __restrict__ feat,
    float* __restrict__ out)
{
    __shared__ float xs[CR][WW];     // 16 KB
    __shared__ float wg[KK][WW];     // 12.25 KB

    const int gs  = blockIdx.x & (GSPLIT - 1);
    const int bh  = blockIdx.x >> 2;       // b*H + h
    const int b   = bh >> 6;
    const int h   = bh & 63;
    const int tid = threadIdx.x;

    // load x row tile: 64 ch x 64 w, coalesced
    {
        const int wl = tid & 63;
        const int o0 = tid >> 6;           // 0..3
#pragma unroll
        for (int i = 0; i < 16; ++i) {
            const int o = o0 + i * 4;
            xs[o][wl] = x[(size_t)(b * CR + o) * HWP + h * WW + wl];
        }
    }
    __syncthreads();

    const int wl = tid & 63;               // lane -> w column
    const int cl = tid >> 6;               // 0..3 -> 4 channels each

    const int g0 = gs * (NG / GSPLIT);     // 4 groups per block
    for (int gi = 0; gi < NG / GSPLIT; ++gi) {
        const int g = g0 + gi;

        // ---- conv2: dynamic weights for this group: wg[k][w] ----
        for (int idx = tid; idx < KK * WW; idx += 256) {
            const int k    = idx >> 6;     // wave-uniform (64 lanes per k)
            const int wcol = idx & 63;
            const int o2   = g * KK + k;
            const float* w2p = w2 + o2 * CR;
            float acc = b2[o2];
#pragma unroll 8
            for (int c = 0; c < CR; ++c)
                acc = fmaf(w2p[c], xs[c][wcol], acc);
            wg[k][wcol] = acc;
        }
        __syncthreads();

        // ---- aggregation: 4 channels per thread ----
        const int cbase = g * GC + cl * 4;
        float acc[4] = {0.f, 0.f, 0.f, 0.f};
#pragma unroll
        for (int k = 0; k < KK; ++k) {
            const int di = k / KS - 3;
            const int dj = k % KS - 3;
            const int hh = h + di;
            const int ww = wl + dj;
            if (hh >= 0 && hh < HH && ww >= 0 && ww < WW) {
                const float wt = wg[k][wl];
                const float* fp = feat + ((size_t)(b * CC + cbase) * HH + hh) * WW + ww;
#pragma unroll
                for (int j = 0; j < 4; ++j)
                    acc[j] = fmaf(wt, fp[(size_t)j * HWP], acc[j]);
            }
        }

        // ---- residual + store, coalesced ----
        const size_t base = ((size_t)(b * CC + cbase) * HH + h) * WW + wl;
#pragma unroll
        for (int j = 0; j < 4; ++j)
            out[base + (size_t)j * HWP] = acc[j] + feat[base + (size_t)j * HWP];

        __syncthreads();   // before next group overwrites wg
    }
}

extern "C" void kernel_launch(void* const* d_in, const int* in_sizes, int n_in,
                              void* d_out, int out_size, void* d_ws, size_t ws_size,
                              hipStream_t stream) {
    const float* feature = (const float*)d_in[0];
    const float* guide   = (const float*)d_in[1];
    const float* w1      = (const float*)d_in[2];
    const float* gamma   = (const float*)d_in[3];
    const float* beta    = (const float*)d_in[4];
    const float* mean    = (const float*)d_in[5];
    const float* var     = (const float*)d_in[6];
    const float* w2      = (const float*)d_in[7];
    const float* b2      = (const float*)d_in[8];
    float* out = (float*)d_out;
    float* xbuf = (float*)d_ws;            // B*CR*HW floats = 4 MB

    conv1_bn_relu<<<256, 256, 0, stream>>>(guide, w1, gamma, beta, mean, var, xbuf);
    conv2_agg<<<BN * HH * GSPLIT, 256, 0, stream>>>(xbuf, w2, b2, feature, out);
}

// Round 2
// 150.349 us; speedup vs baseline: 1.9625x; 1.9625x over previous
//
#include <hip/hip_runtime.h>

// B=4, C=256, CR=64, H=W=64, K=7, KK=49, GROUPS=16, GC=16
#define BN_EPS 1e-5f

typedef __bf16 bf16_t;
typedef __bf16 bf16x8 __attribute__((ext_vector_type(8)));
typedef __bf16 bf16x2 __attribute__((ext_vector_type(2)));
typedef float  floatx4 __attribute__((ext_vector_type(4)));

#define MFMA16(a, b, c) __builtin_amdgcn_mfma_f32_16x16x32_bf16((a), (b), (c), 0, 0, 0)

static __device__ __forceinline__ bf16_t f2b(float f) { return (bf16_t)f; }

// ---------------------------------------------------------------------------
// Kernel 1: xT[b][h*64+p][o] = bf16( ReLU(BN( sum_c w1[o][c]*guide[b][c][h][p] )) )
// One block per (b, h). MFMA 16x16x32 bf16: A = w1 [64 o x 256 c] (c-contig),
// B = guideT [64 p x 256 c] (transposed in LDS). Output stored TRANSPOSED
// (p-major, c-minor, bf16) so kernel 2 can stage its B-operand with uint4.
// ---------------------------------------------------------------------------
#define K1P 264   // bf16 pitch for 256-c rows (+8 pad: row step = 528 B, 16B-aligned, 2-way banks)

__global__ __launch_bounds__(256) void conv1_mfma(
    const float* __restrict__ guide, const float* __restrict__ w1,
    const float* __restrict__ gamma, const float* __restrict__ beta,
    const float* __restrict__ mean,  const float* __restrict__ var,
    bf16_t* __restrict__ xT)
{
    __shared__ __attribute__((aligned(16))) bf16_t w1s[64 * K1P];  // [o][c] 33.8 KB
    __shared__ __attribute__((aligned(16))) bf16_t gTs[64 * K1P];  // [p][c] 33.8 KB

    const int b = blockIdx.x >> 6;
    const int h = blockIdx.x & 63;
    const int t = threadIdx.x;

    // stage w1 -> bf16 [o][c]: float4 reads, 4x b16 (merged b64) writes
#pragma unroll
    for (int i = 0; i < 16; ++i) {
        const int idx = i * 256 + t;          // 4096 float4 chunks
        const int o = idx >> 6, cq = idx & 63;
        const float4 v = *(const float4*)(w1 + o * 256 + cq * 4);
        bf16_t* d = &w1s[o * K1P + cq * 4];
        d[0] = f2b(v.x); d[1] = f2b(v.y); d[2] = f2b(v.z); d[3] = f2b(v.w);
    }
    // stage guide row -> transposed bf16 [p][c]: coalesced reads over p, pack 2 c per write
#pragma unroll
    for (int i = 0; i < 32; ++i) {
        const int idx = i * 256 + t;          // 8192 c-pair x p units
        const int c2 = idx >> 6, p = idx & 63;
        const float g0 = guide[(size_t)(b * 256 + 2 * c2) * 4096 + h * 64 + p];
        const float g1 = guide[(size_t)(b * 256 + 2 * c2 + 1) * 4096 + h * 64 + p];
        bf16x2 pk; pk[0] = f2b(g0); pk[1] = f2b(g1);
        *(bf16x2*)&gTs[p * K1P + 2 * c2] = pk;
    }
    __syncthreads();

    const int wv = t >> 6;            // M-tile (16 o's)
    const int ln = t & 63;
    const int l15 = ln & 15, q = ln >> 4;

    floatx4 acc[4] = {};              // 4 N-tiles of 16 p
    const bf16_t* ap = &w1s[(wv * 16 + l15) * K1P];
    const bf16_t* bp = &gTs[l15 * K1P];
#pragma unroll
    for (int ks = 0; ks < 8; ++ks) {
        const bf16x8 a = *(const bf16x8*)(ap + ks * 32 + q * 8);
#pragma unroll
        for (int nt = 0; nt < 4; ++nt) {
            const bf16x8 bb = *(const bf16x8*)(bp + nt * 16 * K1P + ks * 32 + q * 8);
            acc[nt] = MFMA16(a, bb, acc[nt]);
        }
    }

    // BN + ReLU + transposed bf16 store: lane holds rows o=wv*16+q*4+j, col p=nt*16+l15
    float inv4[4], bia4[4];
#pragma unroll
    for (int j = 0; j < 4; ++j) {
        const int o = wv * 16 + q * 4 + j;
        const float iv = gamma[o] * rsqrtf(var[o] + BN_EPS);
        inv4[j] = iv;
        bia4[j] = beta[o] - mean[o] * iv;
    }
#pragma unroll
    for (int nt = 0; nt < 4; ++nt) {
        const int pc = nt * 16 + l15;
        bf16_t* d = xT + ((size_t)b * 4096 + h * 64 + pc) * 64 + wv * 16 + q * 4;
#pragma unroll
        for (int j = 0; j < 4; ++j) {
            const float v = fmaf(acc[nt][j], inv4[j], bia4[j]);
            d[j] = f2b(fmaxf(v, 0.f));    // 4 consecutive o -> merged 8B store
        }
    }
}

// ---------------------------------------------------------------------------
// Kernel 2: per block = (b, row-pair h0..h0+1, group-quad).
//  Phase A: stage xsT [128 p][64 c] bf16 from xT (uint4, conflict-light).
//  Phase B (per group): stage w2 slab [64 k(pad)][64 c] bf16; MFMA
//    wg[64k x 128p] = w2g * x; +bias; store k<49 rows to wgs (fp32 LDS).
//  Phase C (per group): fp32 aggregation: thread = (4 w, row, 2 ch),
//    register 10-wide feature window reused across 7 dj; + residual.
// ---------------------------------------------------------------------------
#define XSP 72    // bf16 pitch (144 B rows, 16B-aligned)
#define W2P 72
#define WGP 132   // float pitch (528 B rows, 16B-aligned, breaks 4-way store conflicts)

__global__ __launch_bounds__(256) void conv2_mfma_agg(
    const bf16_t* __restrict__ xT, const float* __restrict__ w2,
    const float* __restrict__ b2,  const float* __restrict__ feat,
    float* __restrict__ out)
{
    __shared__ __attribute__((aligned(16))) bf16_t xsT[128 * XSP];  // 18.0 KB
    __shared__ __attribute__((aligned(16))) bf16_t w2s[64 * W2P];   //  9.0 KB
    __shared__ __attribute__((aligned(16))) float  wgs[49 * WGP];   // 25.9 KB

    const int gq = blockIdx.x & 3;
    const int bh = blockIdx.x >> 2;
    const int b  = bh >> 5;
    const int h0 = (bh & 31) * 2;
    const int t  = threadIdx.x;

    // Phase A: stage xsT (two contiguous rows of xT)
    {
        const bf16_t* src = xT + ((size_t)b * 4096 + h0 * 64) * 64;
#pragma unroll
        for (int i = 0; i < 4; ++i) {
            const int u = i * 256 + t;        // 1024 8-elem chunks
            const int p = u >> 3, cq = u & 7;
            *(uint4*)&xsT[p * XSP + cq * 8] = *(const uint4*)(src + p * 64 + cq * 8);
        }
    }

    for (int gi = 0; gi < 4; ++gi) {
        const int g = gq * 4 + gi;
        if (gi) __syncthreads();              // prev group's agg done before reusing w2s/wgs

        // stage w2 slab -> bf16 [k][c], zero rows k>=49
#pragma unroll
        for (int i = 0; i < 4; ++i) {
            const int u = i * 256 + t;        // 1024 float4 chunks
            const int k = u >> 4, cq = u & 15;
            float4 v = {0.f, 0.f, 0.f, 0.f};
            if (k < 49) v = *(const float4*)(w2 + (size_t)(g * 49 + k) * 64 + cq * 4);
            bf16_t* d = &w2s[k * W2P + cq * 4];
            d[0] = f2b(v.x); d[1] = f2b(v.y); d[2] = f2b(v.z); d[3] = f2b(v.w);
        }
        __syncthreads();

        // Phase B: MFMA wg = w2g (64x64) * xs (64c x 128p)
        {
            const int wv = t >> 6, ln = t & 63;
            const int l15 = ln & 15, q = ln >> 4;
            floatx4 acc[8] = {};
            const bf16_t* ap = &w2s[(wv * 16 + l15) * W2P];
            const bf16x8 a0 = *(const bf16x8*)(ap + q * 8);
            const bf16x8 a1 = *(const bf16x8*)(ap + 32 + q * 8);
#pragma unroll
            for (int nt = 0; nt < 8; ++nt) {
                const bf16_t* bp = &xsT[(nt * 16 + l15) * XSP + q * 8];
                acc[nt] = MFMA16(a0, *(const bf16x8*)(bp), acc[nt]);
                acc[nt] = MFMA16(a1, *(const bf16x8*)(bp + 32), acc[nt]);
            }
            const int krow = wv * 16 + q * 4;
            float bias[4];
#pragma unroll
            for (int j = 0; j < 4; ++j)
                bias[j] = (krow + j < 49) ? b2[g * 49 + krow + j] : 0.f;
#pragma unroll
            for (int nt = 0; nt < 8; ++nt) {
                const int pc = nt * 16 + l15;
#pragma unroll
                for (int j = 0; j < 4; ++j) {
                    const int k = krow + j;
                    if (k < 49) wgs[k * WGP + pc] = acc[nt][j] + bias[j];
                }
            }
        }
        __syncthreads();

        // Phase C: aggregation + residual (fp32)
        {
            const int wq = t & 15;            // 4 w's
            const int r  = (t >> 4) & 1;      // row within pair
            const int cp = t >> 5;            // 2 channels
            const int w0 = wq * 4;
            const int ch0 = g * 16 + cp * 2;
            const int hr = h0 + r;

            float acc0[4] = {0.f, 0.f, 0.f, 0.f};
            float acc1[4] = {0.f, 0.f, 0.f, 0.f};
#pragma unroll
            for (int di = 0; di < 7; ++di) {
                const int hh = hr + di - 3;
                if (hh < 0 || hh >= 64) continue;
                const float* fp0 = feat + ((size_t)(b * 256 + ch0) * 64 + hh) * 64;
                const float* fp1 = fp0 + 4096;
                float f0[10], f1[10];
#pragma unroll
                for (int j = 0; j < 10; ++j) {
                    const int ww = w0 - 3 + j;
                    const bool ok = (ww >= 0) && (ww < 64);
                    f0[j] = ok ? fp0[ww] : 0.f;
                    f1[j] = ok ? fp1[ww] : 0.f;
                }
                const float* wrow = &wgs[(di * 7) * WGP + r * 64 + w0];
#pragma unroll
                for (int dj = 0; dj < 7; ++dj) {
                    const floatx4 wv4 = *(const floatx4*)(wrow + dj * WGP);
#pragma unroll
                    for (int x = 0; x < 4; ++x) {
                        acc0[x] = fmaf(wv4[x], f0[x + dj], acc0[x]);
                        acc1[x] = fmaf(wv4[x], f1[x + dj], acc1[x]);
                    }
                }
            }
            const size_t ob = ((size_t)(b * 256 + ch0) * 64 + hr) * 64 + w0;
            const float4 r0 = *(const float4*)(feat + ob);
            const float4 r1 = *(const float4*)(feat + ob + 4096);
            float4 o0, o1;
            o0.x = acc0[0] + r0.x; o0.y = acc0[1] + r0.y; o0.z = acc0[2] + r0.z; o0.w = acc0[3] + r0.w;
            o1.x = acc1[0] + r1.x; o1.y = acc1[1] + r1.y; o1.z = acc1[2] + r1.z; o1.w = acc1[3] + r1.w;
            *(float4*)(out + ob) = o0;
            *(float4*)(out + ob + 4096) = o1;
        }
    }
}

extern "C" void kernel_launch(void* const* d_in, const int* in_sizes, int n_in,
                              void* d_out, int out_size, void* d_ws, size_t ws_size,
                              hipStream_t stream) {
    const float* feature = (const float*)d_in[0];
    const float* guide   = (const float*)d_in[1];
    const float* w1      = (const float*)d_in[2];
    const float* gamma   = (const float*)d_in[3];
    const float* beta    = (const float*)d_in[4];
    const float* mean    = (const float*)d_in[5];
    const float* var     = (const float*)d_in[6];
    const float* w2      = (const float*)d_in[7];
    const float* b2      = (const float*)d_in[8];
    float* out = (float*)d_out;
    bf16_t* xT = (bf16_t*)d_ws;              // 4*4096*64 bf16 = 2 MB

    conv1_mfma<<<4 * 64, 256, 0, stream>>>(guide, w1, gamma, beta, mean, var, xT);
    conv2_mfma_agg<<<4 * 32 * 4, 256, 0, stream>>>(xT, w2, b2, feature, out);
}

// Round 3
// 137.761 us; speedup vs baseline: 2.1418x; 1.0914x over previous
//
#include <hip/hip_runtime.h>

// B=4, C=256, CR=64, H=W=64, K=7, KK=49, GROUPS=16, GC=16
#define BN_EPS 1e-5f

typedef __bf16 bf16_t;
typedef __bf16 bf16x8 __attribute__((ext_vector_type(8)));
typedef __bf16 bf16x4 __attribute__((ext_vector_type(4)));
typedef float  floatx4 __attribute__((ext_vector_type(4)));

#define MFMA16(a, b, c) __builtin_amdgcn_mfma_f32_16x16x32_bf16((a), (b), (c), 0, 0, 0)

// ws layout
#define W1B_OFF 0            // 64*256 bf16  = 32768 B   (w1 * bn_inv, bf16)
#define W2B_OFF 32768        // 784*64 bf16  = 100352 B
#define B1_OFF  133120       // 64 fp32      (bn bias)

// ---------------------------------------------------------------------------
// prep: fold BN scale into w1, convert w1/w2 to bf16, compute bn bias.
// ---------------------------------------------------------------------------
__global__ __launch_bounds__(256) void prep(
    const float* __restrict__ w1, const float* __restrict__ gamma,
    const float* __restrict__ beta, const float* __restrict__ mean,
    const float* __restrict__ var, const float* __restrict__ w2,
    bf16_t* __restrict__ w1b, bf16_t* __restrict__ w2b, float* __restrict__ bias1)
{
    const int idx = blockIdx.x * 256 + threadIdx.x;
    if (idx < 16384) {
        const int o = idx >> 8;
        const float inv = gamma[o] * rsqrtf(var[o] + BN_EPS);
        w1b[idx] = (bf16_t)(w1[idx] * inv);
        if (idx < 64) {
            const float iv = gamma[idx] * rsqrtf(var[idx] + BN_EPS);
            bias1[idx] = beta[idx] - mean[idx] * iv;
        }
    } else if (idx < 16384 + 50176) {
        const int j = idx - 16384;
        w2b[j] = (bf16_t)w2[j];
    }
}

// ---------------------------------------------------------------------------
// fused: per block = (b, h-pair, g-pair). 1024 blocks x 256 threads.
//  conv1 (MFMA, direct-global frags) -> xsT[128p][64c] bf16 in LDS
//  per group: Phase B MFMA wg[49k][128p] -> wgs bf16 LDS; Phase C fp32 agg.
// LDS = 31.4 KB -> 4 blocks/CU co-resident (grid == 4*256).
// ---------------------------------------------------------------------------
#define XSP 72    // bf16 pitch (144 B rows: 2-way banks on frag reads = free)
#define WGP 132   // bf16 pitch (264 B rows, 8B-aligned reads)

__global__ __launch_bounds__(256, 4) void fused(
    const float* __restrict__ guide, const bf16_t* __restrict__ w1b,
    const float* __restrict__ bias1, const bf16_t* __restrict__ w2b,
    const float* __restrict__ b2,    const float* __restrict__ feat,
    float* __restrict__ out)
{
    __shared__ __attribute__((aligned(16))) bf16_t xsT[128 * XSP];  // 18.0 KB
    __shared__ __attribute__((aligned(16))) bf16_t wgs[49 * WGP];   // 12.9 KB

    const int gp = blockIdx.x & 7;
    const int bh = blockIdx.x >> 3;
    const int b  = bh >> 5;
    const int h0 = (bh & 31) * 2;
    const int t  = threadIdx.x;
    const int wv = t >> 6, ln = t & 63, l15 = ln & 15, q = ln >> 4;

    // ---- conv1 in-block: x[o][p] = ReLU(w1b . guide + bias1), store xsT[p][o]
    {
        floatx4 acc[4][2] = {};
        const float* gbase = guide + (size_t)b * 256 * 4096 + h0 * 64;
        for (int ks = 0; ks < 8; ++ks) {
            bf16x8 bf[2];
#pragma unroll
            for (int nt = 0; nt < 2; ++nt) {
                const int p = wv * 32 + nt * 16 + l15;
                const float* gpp = gbase + (size_t)(ks * 32 + q * 8) * 4096 + p;
                bf16x8 v;
#pragma unroll
                for (int j = 0; j < 8; ++j) v[j] = (bf16_t)gpp[(size_t)j * 4096];
                bf[nt] = v;
            }
#pragma unroll
            for (int mt = 0; mt < 4; ++mt) {
                const bf16x8 a = *(const bf16x8*)(w1b + (mt * 16 + l15) * 256 + ks * 32 + q * 8);
                acc[mt][0] = MFMA16(a, bf[0], acc[mt][0]);
                acc[mt][1] = MFMA16(a, bf[1], acc[mt][1]);
            }
        }
#pragma unroll
        for (int mt = 0; mt < 4; ++mt) {
            float bi[4];
#pragma unroll
            for (int j = 0; j < 4; ++j) bi[j] = bias1[mt * 16 + q * 4 + j];
#pragma unroll
            for (int nt = 0; nt < 2; ++nt) {
                const int p = wv * 32 + nt * 16 + l15;
                bf16x4 v;
#pragma unroll
                for (int j = 0; j < 4; ++j)
                    v[j] = (bf16_t)fmaxf(acc[mt][nt][j] + bi[j], 0.f);
                *(bf16x4*)&xsT[p * XSP + mt * 16 + q * 4] = v;
            }
        }
    }
    __syncthreads();

    for (int gi = 0; gi < 2; ++gi) {
        const int g = gp * 2 + gi;
        if (gi) __syncthreads();          // prior Phase C done before wgs reuse

        // ---- Phase B: wg[k][p] = w2g . x  (+b2), bf16 into wgs ----
        {
            floatx4 acc[4][2] = {};
#pragma unroll
            for (int ks = 0; ks < 2; ++ks) {
                bf16x8 bfr[2];
#pragma unroll
                for (int nt = 0; nt < 2; ++nt) {
                    const int p = wv * 32 + nt * 16 + l15;
                    bfr[nt] = *(const bf16x8*)&xsT[p * XSP + ks * 32 + q * 8];
                }
#pragma unroll
                for (int mt = 0; mt < 4; ++mt) {
                    int row = g * 49 + mt * 16 + l15;
                    row = row > 783 ? 783 : row;   // pad rows: harmless, never stored
                    const bf16x8 a = *(const bf16x8*)(w2b + row * 64 + ks * 32 + q * 8);
                    acc[mt][0] = MFMA16(a, bfr[0], acc[mt][0]);
                    acc[mt][1] = MFMA16(a, bfr[1], acc[mt][1]);
                }
            }
#pragma unroll
            for (int mt = 0; mt < 4; ++mt) {
#pragma unroll
                for (int j = 0; j < 4; ++j) {
                    const int k = mt * 16 + q * 4 + j;
                    if (k < 49) {
                        const float bias = b2[g * 49 + k];
#pragma unroll
                        for (int nt = 0; nt < 2; ++nt) {
                            const int p = wv * 32 + nt * 16 + l15;
                            wgs[k * WGP + p] = (bf16_t)(acc[mt][nt][j] + bias);
                        }
                    }
                }
            }
        }
        __syncthreads();

        // ---- Phase C: aggregation + residual (fp32, float4 windows) ----
        {
            const int wq = t & 15, r = (t >> 4) & 1, cp = t >> 5;
            const int w0 = wq * 4;
            const int ch0 = g * 16 + cp * 2;
            const int hr = h0 + r;
            float a0[4] = {0.f, 0.f, 0.f, 0.f}, a1[4] = {0.f, 0.f, 0.f, 0.f};
#pragma unroll
            for (int di = 0; di < 7; ++di) {
                const int hh = hr + di - 3;
                if (hh < 0 || hh >= 64) continue;
                const float* r0 = feat + ((size_t)(b * 256 + ch0) * 64 + hh) * 64;
                const float* r1 = r0 + 4096;
                float4 L0 = {0,0,0,0}, L1 = {0,0,0,0}, R0 = {0,0,0,0}, R1 = {0,0,0,0};
                if (wq > 0)  { L0 = *(const float4*)(r0 + w0 - 4); L1 = *(const float4*)(r1 + w0 - 4); }
                const float4 M0 = *(const float4*)(r0 + w0);
                const float4 M1 = *(const float4*)(r1 + w0);
                if (wq < 15) { R0 = *(const float4*)(r0 + w0 + 4); R1 = *(const float4*)(r1 + w0 + 4); }
                float f0[10], f1[10];
                f0[0]=L0.y; f0[1]=L0.z; f0[2]=L0.w; f0[3]=M0.x; f0[4]=M0.y;
                f0[5]=M0.z; f0[6]=M0.w; f0[7]=R0.x; f0[8]=R0.y; f0[9]=R0.z;
                f1[0]=L1.y; f1[1]=L1.z; f1[2]=L1.w; f1[3]=M1.x; f1[4]=M1.y;
                f1[5]=M1.z; f1[6]=M1.w; f1[7]=R1.x; f1[8]=R1.y; f1[9]=R1.z;
                const bf16_t* wrow = &wgs[(di * 7) * WGP + r * 64 + w0];
#pragma unroll
                for (int dj = 0; dj < 7; ++dj) {
                    const bf16x4 wb = *(const bf16x4*)(wrow + dj * WGP);
#pragma unroll
                    for (int x = 0; x < 4; ++x) {
                        const float wf = (float)wb[x];
                        a0[x] = fmaf(wf, f0[x + dj], a0[x]);
                        a1[x] = fmaf(wf, f1[x + dj], a1[x]);
                    }
                }
            }
            const size_t ob = ((size_t)(b * 256 + ch0) * 64 + hr) * 64 + w0;
            const float4 q0 = *(const float4*)(feat + ob);
            const float4 q1 = *(const float4*)(feat + ob + 4096);
            float4 o0, o1;
            o0.x = a0[0] + q0.x; o0.y = a0[1] + q0.y; o0.z = a0[2] + q0.z; o0.w = a0[3] + q0.w;
            o1.x = a1[0] + q1.x; o1.y = a1[1] + q1.y; o1.z = a1[2] + q1.z; o1.w = a1[3] + q1.w;
            *(float4*)(out + ob) = o0;
            *(float4*)(out + ob + 4096) = o1;
        }
    }
}

extern "C" void kernel_launch(void* const* d_in, const int* in_sizes, int n_in,
                              void* d_out, int out_size, void* d_ws, size_t ws_size,
                              hipStream_t stream) {
    const float* feature = (const float*)d_in[0];
    const float* guide   = (const float*)d_in[1];
    const float* w1      = (const float*)d_in[2];
    const float* gamma   = (const float*)d_in[3];
    const float* beta    = (const float*)d_in[4];
    const float* mean    = (const float*)d_in[5];
    const float* var     = (const float*)d_in[6];
    const float* w2      = (const float*)d_in[7];
    const float* b2      = (const float*)d_in[8];
    float* out = (float*)d_out;

    char* ws = (char*)d_ws;
    bf16_t* w1b   = (bf16_t*)(ws + W1B_OFF);
    bf16_t* w2b   = (bf16_t*)(ws + W2B_OFF);
    float*  bias1 = (float*) (ws + B1_OFF);

    prep<<<(16384 + 50176 + 255) / 256, 256, 0, stream>>>(
        w1, gamma, beta, mean, var, w2, w1b, w2b, bias1);
    fused<<<1024, 256, 0, stream>>>(guide, w1b, bias1, w2b, b2, feature, out);
}